// Round 5
// baseline (464.763 us; speedup 1.0000x reference)
//
#include <hip/hip_runtime.h>
#include <hip/hip_bf16.h>
#include <math.h>

#define BB 2
#define SS 2048
#define DIM 1024
#define NH 16
#define DH 64

typedef __bf16 bf16x8 __attribute__((ext_vector_type(8)));
typedef float f32x4 __attribute__((ext_vector_type(4)));

__device__ __forceinline__ void glds16(const __hip_bfloat16* g, __hip_bfloat16* l) {
    __builtin_amdgcn_global_load_lds(
        (const __attribute__((address_space(1))) void*)g,
        (__attribute__((address_space(3))) void*)l, 16, 0, 0);
}

// ---------------- prep: split fp32 -> bf16 hi + lo ----------------
__global__ void split_f32(const float4* __restrict__ in,
                          ushort4* __restrict__ hi, ushort4* __restrict__ lo) {
    int i = blockIdx.x * 256 + threadIdx.x;
    float4 v = in[i];
    ushort4 h, l;
    __hip_bfloat16 t;
    t = __float2bfloat16(v.x); h.x = *(ushort*)&t; t = __float2bfloat16(v.x - __bfloat162float(t)); l.x = *(ushort*)&t;
    t = __float2bfloat16(v.y); h.y = *(ushort*)&t; t = __float2bfloat16(v.y - __bfloat162float(t)); l.y = *(ushort*)&t;
    t = __float2bfloat16(v.z); h.z = *(ushort*)&t; t = __float2bfloat16(v.z - __bfloat162float(t)); l.z = *(ushort*)&t;
    t = __float2bfloat16(v.w); h.w = *(ushort*)&t; t = __float2bfloat16(v.w - __bfloat162float(t)); l.w = *(ushort*)&t;
    hi[i] = h; lo[i] = l;
}

// ------- prep: transpose all 4 W [K,N] -> [N,K], split hi/lo (one launch) -------
__global__ void trans_split4(const float* __restrict__ Wq, const float* __restrict__ Wk,
                             const float* __restrict__ Wv, const float* __restrict__ Wo,
                             __hip_bfloat16* __restrict__ T3hi, __hip_bfloat16* __restrict__ T3lo,
                             __hip_bfloat16* __restrict__ Tohi, __hip_bfloat16* __restrict__ Tolo) {
    int z = blockIdx.z;
    const float* W = (z == 0) ? Wq : (z == 1) ? Wk : (z == 2) ? Wv : Wo;
    __hip_bfloat16* Thi = (z < 3) ? T3hi + (size_t)z * DIM * DIM : Tohi;
    __hip_bfloat16* Tlo = (z < 3) ? T3lo + (size_t)z * DIM * DIM : Tolo;
    __shared__ float tile[32][33];
    int k0 = blockIdx.x * 32, n0 = blockIdx.y * 32;
    int t = threadIdx.x;
    int r = t >> 3, c = (t & 7) << 2;
    float4 v = *(const float4*)&W[(size_t)(k0 + r) * DIM + n0 + c];
    tile[r][c] = v.x; tile[r][c + 1] = v.y; tile[r][c + 2] = v.z; tile[r][c + 3] = v.w;
    __syncthreads();
    size_t base = (size_t)(n0 + r) * DIM + k0 + c;
#pragma unroll
    for (int i = 0; i < 4; ++i) {
        float x = tile[c + i][r];
        __hip_bfloat16 h = __float2bfloat16(x);
        Thi[base + i] = h;
        Tlo[base + i] = __float2bfloat16(x - __bfloat162float(h));
    }
}

// ---------------- split-bf16 3-term MFMA GEMM ----------------
#define BM 128
#define BN 64
#define BK 32
__global__ __launch_bounds__(256) void gemm3term(
    const __hip_bfloat16* __restrict__ Ahi, const __hip_bfloat16* __restrict__ Alo,
    const __hip_bfloat16* __restrict__ Bhi, const __hip_bfloat16* __restrict__ Blo,
    const float* __restrict__ b0, const float* __restrict__ b1, const float* __restrict__ b2,
    __hip_bfloat16* __restrict__ oq, __hip_bfloat16* __restrict__ ok,
    __hip_bfloat16* __restrict__ ov, float* __restrict__ of32, int mode) {
    __shared__ alignas(16) __hip_bfloat16 sAh[BM * BK];
    __shared__ alignas(16) __hip_bfloat16 sAl[BM * BK];
    __shared__ alignas(16) __hip_bfloat16 sBh[BN * BK];
    __shared__ alignas(16) __hip_bfloat16 sBl[BN * BK];
    const int K = 1024;
    int tid = threadIdx.x;
    int wave = tid >> 6, lane = tid & 63, quad = lane >> 4, l16 = lane & 15;
    int m0 = blockIdx.y * BM, n0 = blockIdx.x * BN;
    int mo = (wave >> 1) * 64, no = (wave & 1) * 32;

    f32x4 acc[4][2];
#pragma unroll
    for (int i = 0; i < 4; ++i)
#pragma unroll
        for (int j = 0; j < 2; ++j) acc[i][j] = (f32x4){0.f, 0.f, 0.f, 0.f};

    int ar = tid >> 2;
    int ac = (tid & 3) << 3;
    const __hip_bfloat16* gAh = Ahi + (size_t)(m0 + ar) * K + ac;
    const __hip_bfloat16* gAl = Alo + (size_t)(m0 + ar) * K + ac;
    const __hip_bfloat16* gBh = Bhi + (size_t)(n0 + ar) * K + ac;
    const __hip_bfloat16* gBl = Blo + (size_t)(n0 + ar) * K + ac;
    __hip_bfloat16* lAh0 = &sAh[ar * BK + ac];
    __hip_bfloat16* lAh1 = &sAh[(ar + 64) * BK + ac];
    __hip_bfloat16* lAl0 = &sAl[ar * BK + ac];
    __hip_bfloat16* lAl1 = &sAl[(ar + 64) * BK + ac];
    __hip_bfloat16* lBh  = &sBh[ar * BK + ac];
    __hip_bfloat16* lBl  = &sBl[ar * BK + ac];

    for (int k0 = 0; k0 < K; k0 += BK) {
        __syncthreads();
        glds16(gAh + k0, lAh0);
        glds16(gAh + (size_t)64 * K + k0, lAh1);
        glds16(gAl + k0, lAl0);
        glds16(gAl + (size_t)64 * K + k0, lAl1);
        glds16(gBh + k0, lBh);
        glds16(gBl + k0, lBl);
        __syncthreads();

        bf16x8 a_h[4], a_l[4], b_h[2], b_l[2];
#pragma unroll
        for (int i = 0; i < 4; ++i) {
            int off = (mo + i * 16 + l16) * BK + quad * 8;
            a_h[i] = *(const bf16x8*)&sAh[off];
            a_l[i] = *(const bf16x8*)&sAl[off];
        }
#pragma unroll
        for (int j = 0; j < 2; ++j) {
            int off = (no + j * 16 + l16) * BK + quad * 8;
            b_h[j] = *(const bf16x8*)&sBh[off];
            b_l[j] = *(const bf16x8*)&sBl[off];
        }
#pragma unroll
        for (int i = 0; i < 4; ++i)
#pragma unroll
            for (int j = 0; j < 2; ++j) {
                acc[i][j] = __builtin_amdgcn_mfma_f32_16x16x32_bf16(a_h[i], b_h[j], acc[i][j], 0, 0, 0);
                acc[i][j] = __builtin_amdgcn_mfma_f32_16x16x32_bf16(a_h[i], b_l[j], acc[i][j], 0, 0, 0);
                acc[i][j] = __builtin_amdgcn_mfma_f32_16x16x32_bf16(a_l[i], b_h[j], acc[i][j], 0, 0, 0);
            }
    }

    int which = (mode == 1) ? (n0 >> 10) : 0;
    const float* bp = (mode == 0) ? b0 : (which == 0) ? b0 : (which == 1) ? b1 : b2;
#pragma unroll
    for (int i = 0; i < 4; ++i)
#pragma unroll
        for (int j = 0; j < 2; ++j) {
            int gmb = m0 + mo + i * 16 + quad * 4;
            int gn  = n0 + no + j * 16 + l16;
            int nn  = gn & 1023;
            float bb = bp[(mode == 0) ? gn : nn];
#pragma unroll
            for (int r = 0; r < 4; ++r) {
                int gm = gmb + r;
                float v = acc[i][j][r] + bb;
                if (mode == 0) {
                    of32[(size_t)gm * 1024 + gn] = v;
                } else {
                    int b = gm >> 11, s = gm & 2047, h = nn >> 6, d = nn & 63;
                    if (which == 0)
                        oq[(((size_t)(b * NH + h)) * SS + s) * DH + d] = __float2bfloat16(v);
                    else if (which == 1)
                        ok[(((size_t)(b * NH + h)) * SS + s) * DH + d] = __float2bfloat16(v);
                    else
                        ov[(((size_t)(b * NH + h)) * DH + d) * SS + s] = __float2bfloat16(v);
                }
            }
        }
}

// -------- flash attention v3: no-max softmax, key-split via blockIdx.z --------
#define PSTRIDE 132
__global__ __launch_bounds__(256, 8) void flash_split(
        const __hip_bfloat16* __restrict__ Q,
        const __hip_bfloat16* __restrict__ K,
        const __hip_bfloat16* __restrict__ Vt,
        const float* __restrict__ mask,
        __hip_bfloat16* __restrict__ Op0, __hip_bfloat16* __restrict__ Op1,
        float* __restrict__ lp0, float* __restrict__ lp1) {
    int bh = blockIdx.y;
    int b = bh >> 4, h = bh & (NH - 1);
    int q0 = blockIdx.x * 64;
    int z  = blockIdx.z;
    __hip_bfloat16* Op = z ? Op1 : Op0;
    float*          lp = z ? lp1 : lp0;
    int tid = threadIdx.x;
    int wave = tid >> 6, lane = tid & 63, quad = lane >> 4, l16 = lane & 15;

    __shared__ __hip_bfloat16 Pl[4][16][PSTRIDE];

    const float SC  = 0.125f * 1.44269504f;
    const float PEN = 1000000.0f * 1.44269504f;

    const __hip_bfloat16* Qrow = Q + ((size_t)bh * SS + q0 + wave * 16 + l16) * DH;
    bf16x8 aq0 = *(const bf16x8*)(Qrow + quad * 8);
    bf16x8 aq1 = *(const bf16x8*)(Qrow + 32 + quad * 8);

    const __hip_bfloat16* Kbase = K + (size_t)bh * SS * DH;
    const __hip_bfloat16* Vbase = Vt + (size_t)bh * DH * SS;
    const float* mbase = mask + b * SS;

    bf16x8 vones;
#pragma unroll
    for (int j = 0; j < 8; ++j) vones[j] = (__bf16)1.0f;

    f32x4 O[4];
#pragma unroll
    for (int i = 0; i < 4; ++i) O[i] = (f32x4){0.f, 0.f, 0.f, 0.f};
    f32x4 lacc = (f32x4){0.f, 0.f, 0.f, 0.f};

    const int kbeg = z * (SS / 2), kend = kbeg + SS / 2;
    for (int k0 = kbeg; k0 < kend; k0 += 128) {
#pragma unroll
        for (int nb = 0; nb < 8; ++nb) {
            int kk = k0 + nb * 16;
            const __hip_bfloat16* Kr = Kbase + (size_t)(kk + l16) * DH + quad * 8;
            bf16x8 bk0 = *(const bf16x8*)(Kr);
            bf16x8 bk1 = *(const bf16x8*)(Kr + 32);
            f32x4 s = (f32x4){0.f, 0.f, 0.f, 0.f};
            s = __builtin_amdgcn_mfma_f32_16x16x32_bf16(aq0, bk0, s, 0, 0, 0);
            s = __builtin_amdgcn_mfma_f32_16x16x32_bf16(aq1, bk1, s, 0, 0, 0);
            float pen = PEN * (1.0f - mbase[kk + l16]);
#pragma unroll
            for (int r = 0; r < 4; ++r)
                Pl[wave][quad * 4 + r][nb * 16 + l16] =
                    __float2bfloat16(exp2f(s[r] * SC - pen));
        }
#pragma unroll
        for (int f = 0; f < 4; ++f) {
            bf16x8 ap = *(const bf16x8*)(&Pl[wave][l16][f * 32 + quad * 8]);
            lacc = __builtin_amdgcn_mfma_f32_16x16x32_bf16(ap, vones, lacc, 0, 0, 0);
#pragma unroll
            for (int nb2 = 0; nb2 < 4; ++nb2) {
                const __hip_bfloat16* Vr =
                    Vbase + (size_t)(nb2 * 16 + l16) * SS + k0 + f * 32 + quad * 8;
                bf16x8 bv = *(const bf16x8*)(Vr);
                O[nb2] = __builtin_amdgcn_mfma_f32_16x16x32_bf16(ap, bv, O[nb2], 0, 0, 0);
            }
        }
    }
#pragma unroll
    for (int nb2 = 0; nb2 < 4; ++nb2)
#pragma unroll
        for (int r = 0; r < 4; ++r) {
            size_t row = (size_t)b * SS + q0 + wave * 16 + quad * 4 + r;
            Op[row * (NH * DH) + h * DH + nb2 * 16 + l16] = __float2bfloat16(O[nb2][r]);
        }
    if (l16 == 0) {
#pragma unroll
        for (int r = 0; r < 4; ++r)
            lp[(size_t)bh * SS + q0 + wave * 16 + quad * 4 + r] = lacc[r];
    }
}

// -------- combine: ctx = (O1+O2)/(l1+l2), split hi/lo --------
__global__ __launch_bounds__(256) void combine(
        const __hip_bfloat16* __restrict__ O1, const __hip_bfloat16* __restrict__ O2,
        const float* __restrict__ l1, const float* __restrict__ l2,
        __hip_bfloat16* __restrict__ chi, __hip_bfloat16* __restrict__ clo) {
    int i = blockIdx.x * 256 + threadIdx.x;
    size_t base = (size_t)i * 8;
    int row = i >> 7;
    int h   = (i >> 3) & 15;
    int b = row >> 11, s = row & 2047;
    size_t bhq = ((size_t)(b * NH + h)) * SS + s;
    float linv = 1.0f / (l1[bhq] + l2[bhq]);
    bf16x8 a = *(const bf16x8*)(O1 + base);
    bf16x8 c = *(const bf16x8*)(O2 + base);
    bf16x8 hi, lo;
#pragma unroll
    for (int j = 0; j < 8; ++j) {
        float v = ((float)a[j] + (float)c[j]) * linv;
        __bf16 hv = (__bf16)v;
        hi[j] = hv;
        lo[j] = (__bf16)(v - (float)hv);
    }
    *(bf16x8*)(chi + base) = hi;
    *(bf16x8*)(clo + base) = lo;
}

extern "C" void kernel_launch(void* const* d_in, const int* in_sizes, int n_in,
                              void* d_out, int out_size, void* d_ws, size_t ws_size,
                              hipStream_t stream) {
    const float* X    = (const float*)d_in[0];
    const float* mask = (const float*)d_in[1];
    const float* Wq   = (const float*)d_in[2];
    const float* bq   = (const float*)d_in[3];
    const float* Wk   = (const float*)d_in[4];
    const float* bk   = (const float*)d_in[5];
    const float* Wv   = (const float*)d_in[6];
    const float* bv   = (const float*)d_in[7];
    const float* Wo   = (const float*)d_in[8];
    const float* bo   = (const float*)d_in[9];
    float* out = (float*)d_out;

    const size_t MB = 1u << 20;
    char* ws = (char*)d_ws;
    __hip_bfloat16* Xhi   = (__hip_bfloat16*)(ws);            // 0-8 MB (later ctx_hi)
    __hip_bfloat16* Xlo   = (__hip_bfloat16*)(ws + 8 * MB);   // 8-16 (later ctx_lo)
    __hip_bfloat16* Wt3hi = (__hip_bfloat16*)(ws + 16 * MB);  // 16-22
    __hip_bfloat16* Wt3lo = (__hip_bfloat16*)(ws + 22 * MB);  // 22-28
    __hip_bfloat16* Wothi = (__hip_bfloat16*)(ws + 28 * MB);  // 28-30
    __hip_bfloat16* Wotlo = (__hip_bfloat16*)(ws + 30 * MB);  // 30-32
    __hip_bfloat16* Qw    = (__hip_bfloat16*)(ws + 32 * MB);  // 32-40
    __hip_bfloat16* Kw    = (__hip_bfloat16*)(ws + 40 * MB);  // 40-48
    __hip_bfloat16* Vt    = (__hip_bfloat16*)(ws + 48 * MB);  // 48-56
    // partials alias the dead QKV-weight region (read finished before flash):
    __hip_bfloat16* Op0   = (__hip_bfloat16*)(ws + 16 * MB);  // 16-24
    float*          lp0   = (float*)(ws + 24 * MB);           // 24-24.25
    float*          lp1   = (float*)(ws + 25 * MB);           // 25-25.25
    __hip_bfloat16* Op1   = (__hip_bfloat16*)(ws + 56 * MB);  // 56-64

    split_f32<<<4096, 256, 0, stream>>>((const float4*)X, (ushort4*)Xhi, (ushort4*)Xlo);

    dim3 tgrd(32, 32, 4);
    trans_split4<<<tgrd, 256, 0, stream>>>(Wq, Wk, Wv, Wo, Wt3hi, Wt3lo, Wothi, Wotlo);

    dim3 qkvgrd(3 * DIM / BN, (BB * SS) / BM);   // (48, 32)
    gemm3term<<<qkvgrd, 256, 0, stream>>>(Xhi, Xlo, Wt3hi, Wt3lo, bq, bk, bv,
                                          Qw, Kw, Vt, nullptr, 1);

    dim3 agrd(SS / 64, BB * NH, 2);              // 2048 blocks
    flash_split<<<agrd, 256, 0, stream>>>(Qw, Kw, Vt, mask, Op0, Op1, lp0, lp1);

    combine<<<dim3(2048), 256, 0, stream>>>(Op0, Op1, lp0, lp1, Xhi, Xlo);

    dim3 ogrd(DIM / BN, (BB * SS) / BM);         // (16, 32)
    gemm3term<<<ogrd, 256, 0, stream>>>(Xhi, Xlo, Wothi, Wotlo, bo, nullptr, nullptr,
                                        nullptr, nullptr, nullptr, out, 0);
}